// Round 15
// baseline (117.926 us; speedup 1.0000x reference)
//
#include <hip/hip_runtime.h>
#include <hip/hip_bf16.h>

namespace {

constexpr int Bsz = 64, Cch = 3, Himg = 224, Wimg = 224, Ppat = 16;
constexpr int Dm = 768, NPW = 14, NPATCH = 196, SEQn = 197;
constexpr int Mtot = Bsz * NPATCH;   // 12544
constexpr int Ktot = 768, Ntot = 768;
constexpr int BM = 64, BN = 128, BK = 64;
constexpr int MT = Mtot / BM;        // 196
constexpr int NT = Ntot / BN;        // 6
constexpr int KT = Ktot / BK;        // 12
constexpr int NBLK = MT * NT;        // 1176 (divisible by 8)
constexpr int TA = BM * BK;          // 4096 elems = 8 KB
constexpr int TB = BN * BK;          // 8192 elems = 16 KB
constexpr size_t AP_ELEMS = (size_t)MT * KT * TA;          // 9,633,792
constexpr size_t WT_ELEMS = (size_t)NT * KT * TB;          // 589,824
constexpr size_t WS_NEED = (AP_ELEMS + WT_ELEMS) * 2;      // ~20.4 MB
constexpr int PATCH_BLK = MT * KT;                         // 2352
constexpr int WPREP_BLK = (Ktot / 8) * Ntot / 256;         // 288
constexpr int CLS_BLK = Bsz * Dm / 256;                    // 192

typedef __attribute__((ext_vector_type(8))) short bf16x8;
typedef __attribute__((ext_vector_type(4))) float f32x4;

__device__ inline unsigned short f2bf(float f) {
  __bf16 h = (__bf16)f;  // RNE; clang fuses pairs into v_cvt_pk_bf16_f32
  union { __bf16 h; unsigned short u; } c;
  c.h = h;
  return c.u;
}

union Pack8 { unsigned short s[8]; uint4 v; };

// ---------------- prepass: patchify x -> Ap, W -> Wt, cls row ---------------
// Ap tile (mt,kt) [64x64]: elem (r,k) at (mt*KT+kt)*TA + ((r*BK+k)^((r&7)<<3))
// Wt tile (nb,kt) [128x64]: elem (n',k') at (nb*KT+kt)*TB + ((n'*BK+k')^((n'&7)<<3))
// Pre-swizzled so LINEAR staging (DMA or reg->ds_write at dest t*8+i*1024)
// yields the swizzled LDS image the ds_read_b128 fragment reads expect (m173).
__global__ void prep_kernel(const float* __restrict__ x, const float* __restrict__ W,
                            const float* __restrict__ pos, const float* __restrict__ cls,
                            unsigned short* __restrict__ Ap, unsigned short* __restrict__ Wt,
                            float* __restrict__ out, int nPatchBlk) {
  const int bid = blockIdx.x;
  const int t = threadIdx.x;
  if (bid < nPatchBlk) {  // ---- patchify one 64x64 A-tile (direct store)
    int mt = bid / KT, kt = bid - mt * KT;
    int r = t >> 2, ks = t & 3;           // thread = one 16-px pixel row
    int m = mt * BM + r;
    int b = m / NPATCH;
    int pidx = m - b * NPATCH;
    int ph = pidx / NPW, pw = pidx - ph * NPW;
    int kg = kt * BK + ks * 16;           // multiple of 16 -> pj = 0
    int c = kg >> 8, pi = (kg >> 4) & 15;
    const float* src = x + ((size_t)(b * Cch + c) * Himg + ph * Ppat + pi) * Wimg
                       + pw * Ppat;
    float4 v0 = *reinterpret_cast<const float4*>(src + 0);
    float4 v1 = *reinterpret_cast<const float4*>(src + 4);
    float4 v2 = *reinterpret_cast<const float4*>(src + 8);
    float4 v3 = *reinterpret_cast<const float4*>(src + 12);
    Pack8 p0, p1;
    p0.s[0] = f2bf(v0.x); p0.s[1] = f2bf(v0.y); p0.s[2] = f2bf(v0.z); p0.s[3] = f2bf(v0.w);
    p0.s[4] = f2bf(v1.x); p0.s[5] = f2bf(v1.y); p0.s[6] = f2bf(v1.z); p0.s[7] = f2bf(v1.w);
    p1.s[0] = f2bf(v2.x); p1.s[1] = f2bf(v2.y); p1.s[2] = f2bf(v2.z); p1.s[3] = f2bf(v2.w);
    p1.s[4] = f2bf(v3.x); p1.s[5] = f2bf(v3.y); p1.s[6] = f2bf(v3.z); p1.s[7] = f2bf(v3.w);
    unsigned short* dst = Ap + (size_t)bid * TA;
    int g = r * BK + ks * 16;
    int sw = (r & 7) << 3;
    *reinterpret_cast<uint4*>(dst + (g ^ sw)) = p0.v;
    *reinterpret_cast<uint4*>(dst + ((g + 8) ^ sw)) = p1.v;
  } else if (bid < nPatchBlk + WPREP_BLK) {  // ---- W prep (swizzled tiles)
    int cid = (bid - nPatchBlk) * 256 + t;
    int kc = cid / Ntot;                      // k-chunk of 8 (0..95)
    int n = cid - kc * Ntot;
    int nb = n >> 7;                          // 0..5
    int np = n & 127;
    int kt = kc >> 3;
    int k8 = (kc & 7) * 8;
    Pack8 p;
#pragma unroll
    for (int j = 0; j < 8; ++j) p.s[j] = f2bf(W[(size_t)(kc * 8 + j) * Ntot + n]);
    int sidx = (np * BK + k8) ^ ((np & 7) << 3);
    *reinterpret_cast<uint4*>(Wt + (size_t)(nb * KT + kt) * TB + sidx) = p.v;
  } else {  // ---- class-token row (s = 0)
    int i = (bid - nPatchBlk - WPREP_BLK) * 256 + t;
    int b = i / Dm;
    int d = i - b * Dm;
    out[(size_t)b * (SEQn * Dm) + d] = cls[d] + pos[d];
  }
}

// ---------------- GEMM: R12 + T14 async-STAGE split -------------------------
// Single 24 KB buffer (6 blk/CU, grid 1176 all co-resident — the proven
// occupancy regime) but the next tile is prefetched into REGISTERS during
// compute (L2 latency hides under MFMA), then ds_written after the read-done
// barrier. Replaces the per-step exposed DMA fill of R12. No inline asm;
// compiler inserts the vmcnt/lgkmcnt ordering.
__global__ __launch_bounds__(128, 3)
void gemm_kernel(const unsigned short* __restrict__ Ap, const unsigned short* __restrict__ Wt,
                 const float* __restrict__ bias, const float* __restrict__ pos,
                 float* __restrict__ out) {
  __shared__ unsigned short A[TA];     // 8 KB
  __shared__ unsigned short B[TB];     // 16 KB

  // XCD-chunked bijective swizzle (NBLK % 8 == 0); bn fastest within a chunk
  // -> A-panel reused across the 6 bn's within one XCD's L2.
  const int orig = blockIdx.x;
  const int wg = (orig & 7) * (NBLK / 8) + (orig >> 3);
  const int bm = wg / NT;
  const int bn = wg - bm * NT;

  const int t = threadIdx.x;
  const int lane = t & 63;
  const int wc = t >> 6;               // 2 waves: 1 (M) x 2 (N), each 64x64
  const int fr = lane & 15, fq = lane >> 4;

  const unsigned short* aSrc = Ap + (size_t)(bm * KT) * TA + t * 8;
  const unsigned short* bSrc = Wt + (size_t)(bn * KT) * TB + t * 8;

  // prologue: tile 0 via DMA (no regs needed, syncthreads drains vmcnt)
#pragma unroll
  for (int i = 0; i < 4; ++i)
    __builtin_amdgcn_global_load_lds(
        (const __attribute__((address_space(1))) unsigned int*)(aSrc + i * 1024),
        (__attribute__((address_space(3))) unsigned int*)(&A[t * 8 + i * 1024]),
        16, 0, 0);
#pragma unroll
  for (int i = 0; i < 8; ++i)
    __builtin_amdgcn_global_load_lds(
        (const __attribute__((address_space(1))) unsigned int*)(bSrc + i * 1024),
        (__attribute__((address_space(3))) unsigned int*)(&B[t * 8 + i * 1024]),
        16, 0, 0);
  __syncthreads();

  f32x4 acc[4][4];
#pragma unroll
  for (int mi = 0; mi < 4; ++mi)
#pragma unroll
    for (int ni = 0; ni < 4; ++ni) acc[mi][ni] = {0.f, 0.f, 0.f, 0.f};

  for (int kt = 0; kt < KT; ++kt) {
    // T14 issue-early: prefetch next tile into regs (latency hides under MFMA)
    uint4 pfA[4], pfB[8];
    const bool haveNext = (kt + 1 < KT);
    if (haveNext) {
#pragma unroll
      for (int i = 0; i < 4; ++i)
        pfA[i] = *reinterpret_cast<const uint4*>(aSrc + (kt + 1) * TA + i * 1024);
#pragma unroll
      for (int i = 0; i < 8; ++i)
        pfB[i] = *reinterpret_cast<const uint4*>(bSrc + (kt + 1) * TB + i * 1024);
    }
    // compute current tile from LDS
#pragma unroll
    for (int ks = 0; ks < 2; ++ks) {
      bf16x8 af[4], bfr[4];
#pragma unroll
      for (int mi = 0; mi < 4; ++mi) {
        int row = mi * 16 + fr;
        int idx = (row * BK + ks * 32 + fq * 8) ^ ((row & 7) << 3);
        af[mi] = *reinterpret_cast<const bf16x8*>(&A[idx]);
      }
#pragma unroll
      for (int ni = 0; ni < 4; ++ni) {
        int n = wc * 64 + ni * 16 + fr;
        int idx = (n * BK + ks * 32 + fq * 8) ^ ((n & 7) << 3);
        bfr[ni] = *reinterpret_cast<const bf16x8*>(&B[idx]);
      }
#pragma unroll
      for (int mi = 0; mi < 4; ++mi)
#pragma unroll
        for (int ni = 0; ni < 4; ++ni)
          acc[mi][ni] = __builtin_amdgcn_mfma_f32_16x16x32_bf16(
              af[mi], bfr[ni], acc[mi][ni], 0, 0, 0);
    }
    if (haveNext) {
      __syncthreads();  // all reads of tile kt done -> safe to overwrite
      // T14 write-late: regs arrived during compute; short ds_write burst
#pragma unroll
      for (int i = 0; i < 4; ++i)
        *reinterpret_cast<uint4*>(&A[t * 8 + i * 1024]) = pfA[i];
#pragma unroll
      for (int i = 0; i < 8; ++i)
        *reinterpret_cast<uint4*>(&B[t * 8 + i * 1024]) = pfB[i];
      __syncthreads();  // writes visible before next compute
    }
  }

  // ---- epilogue: R5/R10 pattern (measured WRITE_SIZE == ideal 37.6 MB):
  // per (mi,j) the 4 ni-stores are adjacent, covering 256B contiguous per row.
  const int n0 = bn * BN + wc * 64;
  float bv[4];
#pragma unroll
  for (int ni = 0; ni < 4; ++ni) bv[ni] = bias[n0 + ni * 16 + fr];
#pragma unroll
  for (int mi = 0; mi < 4; ++mi) {
#pragma unroll
    for (int j = 0; j < 4; ++j) {
      int m = bm * BM + mi * 16 + fq * 4 + j;
      int b = m / NPATCH;
      int s = m - b * NPATCH + 1;  // +1: class token at s=0
      float* orow = out + ((size_t)b * SEQn + s) * Dm + n0;
      const float* prow = pos + (size_t)s * Dm + n0;
#pragma unroll
      for (int ni = 0; ni < 4; ++ni) {
        int d = ni * 16 + fr;
        orow[d] = acc[mi][ni][j] + bv[ni] + prow[d];
      }
    }
  }
}

// ---------------- fallback (ws too small): stages A in-kernel ---------------
__global__ __launch_bounds__(512, 6)
void gemm_fb(const float* __restrict__ x, const unsigned short* __restrict__ Wt,
             const float* __restrict__ bias, const float* __restrict__ pos,
             float* __restrict__ out) {
  __shared__ unsigned short As[2][TA];
  __shared__ unsigned short Bs[2][TB];

  const int orig = blockIdx.x;
  const int wg = (orig & 7) * (NBLK / 8) + (orig >> 3);
  const int bm = wg / NT;
  const int bn = wg - bm * NT;

  const int t = threadIdx.x;
  const int lane = t & 63;
  const int wid = t >> 6;              // 8 waves: 2 (M) x 4 (N)
  const int wr = wid >> 2, wc = wid & 3;
  const int fr = lane & 15, fq = lane >> 4;

  const int c4 = t & 15;
  const int r0 = t >> 4;
  int a_base[2];
#pragma unroll
  for (int i = 0; i < 2; ++i) {
    int m = bm * BM + r0 + 32 * i;
    int b = m / NPATCH;
    int pidx = m - b * NPATCH;
    int ph = pidx / NPW;
    int pw = pidx - ph * NPW;
    a_base[i] = ((b * Cch) * Himg + ph * Ppat) * Wimg + pw * Ppat;
  }
  const unsigned short* wt_base = Wt + (size_t)bn * (KT * TB);

  float4 av[2];
  auto LOADA = [&](int kt) {
    int kg = kt * BK + c4 * 4;
    int c = kg >> 8, pi = (kg >> 4) & 15, pj = kg & 15;
    int off = (c * Himg + pi) * Wimg + pj;
#pragma unroll
    for (int i = 0; i < 2; ++i)
      av[i] = *reinterpret_cast<const float4*>(x + a_base[i] + off);
  };
  auto WRITEA = [&](int buf) {
#pragma unroll
    for (int i = 0; i < 2; ++i) {
      int row = r0 + 32 * i;
      int idx = (row * BK + c4 * 4) ^ ((row & 7) << 3);
      ushort4 pk = make_ushort4(f2bf(av[i].x), f2bf(av[i].y), f2bf(av[i].z), f2bf(av[i].w));
      *reinterpret_cast<ushort4*>(&As[buf][idx]) = pk;
    }
  };
  auto STAGEB = [&](int buf, int kt) {
    const unsigned short* src = wt_base + kt * TB + t * 8;
#pragma unroll
    for (int i = 0; i < 2; ++i) {
      __builtin_amdgcn_global_load_lds(
          (const __attribute__((address_space(1))) unsigned int*)(src + i * 4096),
          (__attribute__((address_space(3))) unsigned int*)(&Bs[buf][t * 8 + i * 4096]),
          16, 0, 0);
    }
  };

  f32x4 acc[2][2];
#pragma unroll
  for (int mi = 0; mi < 2; ++mi)
#pragma unroll
    for (int ni = 0; ni < 2; ++ni) acc[mi][ni] = {0.f, 0.f, 0.f, 0.f};

  LOADA(0);
  STAGEB(0, 0);
  WRITEA(0);
  __syncthreads();

  for (int kt = 0; kt < KT; ++kt) {
    const int cur = kt & 1, nxt = cur ^ 1;
    if (kt + 1 < KT) {
      LOADA(kt + 1);
      STAGEB(nxt, kt + 1);
    }
#pragma unroll
    for (int ks = 0; ks < 2; ++ks) {
      bf16x8 af[2], bfr[2];
#pragma unroll
      for (int mi = 0; mi < 2; ++mi) {
        int row = wr * 32 + mi * 16 + fr;
        int idx = (row * BK + ks * 32 + fq * 8) ^ ((row & 7) << 3);
        af[mi] = *reinterpret_cast<const bf16x8*>(&As[cur][idx]);
      }
#pragma unroll
      for (int ni = 0; ni < 2; ++ni) {
        int n = wc * 32 + ni * 16 + fr;
        int idx = (n * BK + ks * 32 + fq * 8) ^ ((n & 7) << 3);
        bfr[ni] = *reinterpret_cast<const bf16x8*>(&Bs[cur][idx]);
      }
#pragma unroll
      for (int mi = 0; mi < 2; ++mi)
#pragma unroll
        for (int ni = 0; ni < 2; ++ni)
          acc[mi][ni] = __builtin_amdgcn_mfma_f32_16x16x32_bf16(
              af[mi], bfr[ni], acc[mi][ni], 0, 0, 0);
    }
    if (kt + 1 < KT) WRITEA(nxt);
    __syncthreads();
  }

  const int n0 = bn * BN + wc * 32;
  float bv[2];
#pragma unroll
  for (int ni = 0; ni < 2; ++ni) bv[ni] = bias[n0 + ni * 16 + fr];
#pragma unroll
  for (int mi = 0; mi < 2; ++mi) {
#pragma unroll
    for (int j = 0; j < 4; ++j) {
      int m = bm * BM + wr * 32 + mi * 16 + fq * 4 + j;
      int b = m / NPATCH;
      int s = m - b * NPATCH + 1;
      float* orow = out + ((size_t)b * SEQn + s) * Dm + n0;
      const float* prow = pos + (size_t)s * Dm + n0;
#pragma unroll
      for (int ni = 0; ni < 2; ++ni) {
        int d = ni * 16 + fr;
        orow[d] = acc[mi][ni][j] + bv[ni] + prow[d];
      }
    }
  }
}

}  // namespace

extern "C" void kernel_launch(void* const* d_in, const int* in_sizes, int n_in,
                              void* d_out, int out_size, void* d_ws, size_t ws_size,
                              hipStream_t stream) {
  const float* x = (const float*)d_in[0];
  const float* W = (const float*)d_in[1];
  const float* bias = (const float*)d_in[2];
  const float* pos = (const float*)d_in[3];
  const float* cls = (const float*)d_in[4];
  float* out = (float*)d_out;

  const bool pure = ws_size >= WS_NEED;
  unsigned short* Ap = (unsigned short*)d_ws;
  unsigned short* Wt = pure ? Ap + AP_ELEMS : Ap;  // fallback: Wt at ws base
  const int nPatchBlk = pure ? PATCH_BLK : 0;

  prep_kernel<<<nPatchBlk + WPREP_BLK + CLS_BLK, 256, 0, stream>>>(
      x, W, pos, cls, Ap, Wt, out, nPatchBlk);
  if (pure)
    gemm_kernel<<<NBLK, 128, 0, stream>>>(Ap, Wt, bias, pos, out);
  else
    gemm_fb<<<NBLK, 512, 0, stream>>>(x, Wt, bias, pos, out);
}

// Round 16
// 40.931 us; speedup vs baseline: 2.8811x; 2.8811x over previous
//
#include <hip/hip_runtime.h>
#include <hip/hip_bf16.h>

namespace {

constexpr int Bsz = 64, Cch = 3, Himg = 224, Wimg = 224, Ppat = 16;
constexpr int Dm = 768, NPW = 14, NPATCH = 196, SEQn = 197;
constexpr int Mtot = Bsz * NPATCH;   // 12544
constexpr int Ktot = 768, Ntot = 768;
constexpr int BM = 64, BN = 128, BK = 64;
constexpr int MT = Mtot / BM;        // 196
constexpr int NT = Ntot / BN;        // 6
constexpr int KT = Ktot / BK;        // 12
constexpr int NBLK = MT * NT;        // 1176 (divisible by 8)
constexpr int TA = BM * BK;          // 4096 elems = 8 KB
constexpr int TB = BN * BK;          // 8192 elems = 16 KB
constexpr size_t AP_ELEMS = (size_t)MT * KT * TA;          // 9,633,792
constexpr size_t WT_ELEMS = (size_t)NT * KT * TB;          // 589,824
constexpr size_t WS_NEED = (AP_ELEMS + WT_ELEMS) * 2;      // ~20.4 MB
constexpr int PATCH_BLK = MT * KT;                         // 2352
constexpr int WPREP_BLK = (Ktot / 8) * Ntot / 256;         // 288
constexpr int CLS_BLK = Bsz * Dm / 256;                    // 192

typedef __attribute__((ext_vector_type(8))) short bf16x8;
typedef __attribute__((ext_vector_type(4))) float f32x4;

__device__ inline unsigned short f2bf(float f) {
  __bf16 h = (__bf16)f;  // RNE; clang fuses pairs into v_cvt_pk_bf16_f32
  union { __bf16 h; unsigned short u; } c;
  c.h = h;
  return c.u;
}

union Pack8 { unsigned short s[8]; uint4 v; };

// ---------------- prepass: patchify x -> Ap, W -> Wt, cls row ---------------
// Ap tile (mt,kt) [64x64]: elem (r,k) at (mt*KT+kt)*TA + ((r*BK+k)^((r&7)<<3))
// Wt tile (nb,kt) [128x64]: elem (n',k') at (nb*KT+kt)*TB + ((n'*BK+k')^((n'&7)<<3))
// Pre-swizzled so LINEAR global_load_lds staging yields the swizzled LDS
// image the ds_read_b128 fragment reads expect (m173 pattern). XOR acts on
// 16B granules, so granule-aligned uint4 writes stay contiguous.
__global__ void prep_kernel(const float* __restrict__ x, const float* __restrict__ W,
                            const float* __restrict__ pos, const float* __restrict__ cls,
                            unsigned short* __restrict__ Ap, unsigned short* __restrict__ Wt,
                            float* __restrict__ out, int nPatchBlk) {
  const int bid = blockIdx.x;
  const int t = threadIdx.x;
  if (bid < nPatchBlk) {  // ---- patchify one 64x64 A-tile (direct store)
    int mt = bid / KT, kt = bid - mt * KT;
    int r = t >> 2, ks = t & 3;           // thread = one 16-px pixel row
    int m = mt * BM + r;
    int b = m / NPATCH;
    int pidx = m - b * NPATCH;
    int ph = pidx / NPW, pw = pidx - ph * NPW;
    int kg = kt * BK + ks * 16;           // multiple of 16 -> pj = 0
    int c = kg >> 8, pi = (kg >> 4) & 15;
    const float* src = x + ((size_t)(b * Cch + c) * Himg + ph * Ppat + pi) * Wimg
                       + pw * Ppat;
    float4 v0 = *reinterpret_cast<const float4*>(src + 0);
    float4 v1 = *reinterpret_cast<const float4*>(src + 4);
    float4 v2 = *reinterpret_cast<const float4*>(src + 8);
    float4 v3 = *reinterpret_cast<const float4*>(src + 12);
    Pack8 p0, p1;
    p0.s[0] = f2bf(v0.x); p0.s[1] = f2bf(v0.y); p0.s[2] = f2bf(v0.z); p0.s[3] = f2bf(v0.w);
    p0.s[4] = f2bf(v1.x); p0.s[5] = f2bf(v1.y); p0.s[6] = f2bf(v1.z); p0.s[7] = f2bf(v1.w);
    p1.s[0] = f2bf(v2.x); p1.s[1] = f2bf(v2.y); p1.s[2] = f2bf(v2.z); p1.s[3] = f2bf(v2.w);
    p1.s[4] = f2bf(v3.x); p1.s[5] = f2bf(v3.y); p1.s[6] = f2bf(v3.z); p1.s[7] = f2bf(v3.w);
    unsigned short* dst = Ap + (size_t)bid * TA;
    int g = r * BK + ks * 16;
    int sw = (r & 7) << 3;
    *reinterpret_cast<uint4*>(dst + (g ^ sw)) = p0.v;
    *reinterpret_cast<uint4*>(dst + ((g + 8) ^ sw)) = p1.v;
  } else if (bid < nPatchBlk + WPREP_BLK) {  // ---- W prep (swizzled tiles)
    int cid = (bid - nPatchBlk) * 256 + t;
    int kc = cid / Ntot;                      // k-chunk of 8 (0..95)
    int n = cid - kc * Ntot;
    int nb = n >> 7;                          // 0..5
    int np = n & 127;
    int kt = kc >> 3;
    int k8 = (kc & 7) * 8;
    Pack8 p;
#pragma unroll
    for (int j = 0; j < 8; ++j) p.s[j] = f2bf(W[(size_t)(kc * 8 + j) * Ntot + n]);
    int sidx = (np * BK + k8) ^ ((np & 7) << 3);
    *reinterpret_cast<uint4*>(Wt + (size_t)(nb * KT + kt) * TB + sidx) = p.v;
  } else {  // ---- class-token row (s = 0)
    int i = (bid - nPatchBlk - WPREP_BLK) * 256 + t;
    int b = i / Dm;
    int d = i - b * Dm;
    out[(size_t)b * (SEQn * Dm) + d] = cls[d] + pos[d];
  }
}

// ---------------- GEMM: 1-WAVE blocks, wave-tile 64x128, single buffer ------
// 64-thread blocks remove the inter-wave barrier convoy: __syncthreads in a
// 1-wave block is just waitcnt+retiring-barrier, so each wave free-runs its
// own {stage -> wait -> compute} cycle; 6 co-resident blocks/CU (24 KB each)
// interleave to cover each other's DMA latency. Wave-tile 64x128 (acc 4x8)
// cuts ds_read per MFMA to 0.375 (24 reads / 64 MFMA per step).
__global__ __launch_bounds__(64, 2)
void gemm_kernel(const unsigned short* __restrict__ Ap, const unsigned short* __restrict__ Wt,
                 const float* __restrict__ bias, const float* __restrict__ pos,
                 float* __restrict__ out) {
  __shared__ unsigned short A[TA];     // 8 KB
  __shared__ unsigned short B[TB];     // 16 KB

  // XCD-chunked bijective swizzle (NBLK % 8 == 0); bn fastest within a chunk
  // -> A-panel reused across the 6 bn's within one XCD's L2.
  const int orig = blockIdx.x;
  const int wg = (orig & 7) * (NBLK / 8) + (orig >> 3);
  const int bm = wg / NT;
  const int bn = wg - bm * NT;

  const int t = threadIdx.x;           // == lane, 0..63
  const int fr = t & 15, fq = t >> 4;  // fq 0..3

  const unsigned short* aSrc = Ap + (size_t)(bm * KT) * TA + t * 8;
  const unsigned short* bSrc = Wt + (size_t)(bn * KT) * TB + t * 8;

  auto STAGE = [&](int kt) {  // 24 x 16B per thread (1 KB per instruction)
#pragma unroll
    for (int i = 0; i < 8; ++i)
      __builtin_amdgcn_global_load_lds(
          (const __attribute__((address_space(1))) unsigned int*)(aSrc + kt * TA + i * 512),
          (__attribute__((address_space(3))) unsigned int*)(&A[t * 8 + i * 512]),
          16, 0, 0);
#pragma unroll
    for (int i = 0; i < 16; ++i)
      __builtin_amdgcn_global_load_lds(
          (const __attribute__((address_space(1))) unsigned int*)(bSrc + kt * TB + i * 512),
          (__attribute__((address_space(3))) unsigned int*)(&B[t * 8 + i * 512]),
          16, 0, 0);
  };

  f32x4 acc[4][8];
#pragma unroll
  for (int mi = 0; mi < 4; ++mi)
#pragma unroll
    for (int ni = 0; ni < 8; ++ni) acc[mi][ni] = {0.f, 0.f, 0.f, 0.f};

  for (int kt = 0; kt < KT; ++kt) {
    STAGE(kt);
    __syncthreads();                   // 1-wave: waitcnt vm/lgkm(0) + retire
#pragma unroll
    for (int ks = 0; ks < 2; ++ks) {
      bf16x8 af[4], bfr[8];
#pragma unroll
      for (int mi = 0; mi < 4; ++mi) {
        int row = mi * 16 + fr;
        int idx = (row * BK + ks * 32 + fq * 8) ^ ((row & 7) << 3);
        af[mi] = *reinterpret_cast<const bf16x8*>(&A[idx]);
      }
#pragma unroll
      for (int ni = 0; ni < 8; ++ni) {
        int n = ni * 16 + fr;
        int idx = (n * BK + ks * 32 + fq * 8) ^ ((n & 7) << 3);
        bfr[ni] = *reinterpret_cast<const bf16x8*>(&B[idx]);
      }
#pragma unroll
      for (int mi = 0; mi < 4; ++mi)
#pragma unroll
        for (int ni = 0; ni < 8; ++ni)
          acc[mi][ni] = __builtin_amdgcn_mfma_f32_16x16x32_bf16(
              af[mi], bfr[ni], acc[mi][ni], 0, 0, 0);
    }
    if (kt + 1 < KT) __syncthreads();  // reads done before next overwrite
  }

  // ---- epilogue: per (mi,j) the 8 ni-stores are adjacent, covering 512B
  // contiguous per row (superset of the R5/R10-proven 256B granule pattern).
  const int n0 = bn * BN;
  float bv[8];
#pragma unroll
  for (int ni = 0; ni < 8; ++ni) bv[ni] = bias[n0 + ni * 16 + fr];
#pragma unroll
  for (int mi = 0; mi < 4; ++mi) {
#pragma unroll
    for (int j = 0; j < 4; ++j) {
      int m = bm * BM + mi * 16 + fq * 4 + j;
      int b = m / NPATCH;
      int s = m - b * NPATCH + 1;  // +1: class token at s=0
      float* orow = out + ((size_t)b * SEQn + s) * Dm + n0;
      const float* prow = pos + (size_t)s * Dm + n0;
#pragma unroll
      for (int ni = 0; ni < 8; ++ni) {
        int d = ni * 16 + fr;
        orow[d] = acc[mi][ni][j] + bv[ni] + prow[d];
      }
    }
  }
}

// ---------------- fallback (ws too small): stages A in-kernel ---------------
__global__ __launch_bounds__(512, 6)
void gemm_fb(const float* __restrict__ x, const unsigned short* __restrict__ Wt,
             const float* __restrict__ bias, const float* __restrict__ pos,
             float* __restrict__ out) {
  __shared__ unsigned short As[2][TA];
  __shared__ unsigned short Bs[2][TB];

  const int orig = blockIdx.x;
  const int wg = (orig & 7) * (NBLK / 8) + (orig >> 3);
  const int bm = wg / NT;
  const int bn = wg - bm * NT;

  const int t = threadIdx.x;
  const int lane = t & 63;
  const int wid = t >> 6;              // 8 waves: 2 (M) x 4 (N)
  const int wr = wid >> 2, wc = wid & 3;
  const int fr = lane & 15, fq = lane >> 4;

  const int c4 = t & 15;
  const int r0 = t >> 4;
  int a_base[2];
#pragma unroll
  for (int i = 0; i < 2; ++i) {
    int m = bm * BM + r0 + 32 * i;
    int b = m / NPATCH;
    int pidx = m - b * NPATCH;
    int ph = pidx / NPW;
    int pw = pidx - ph * NPW;
    a_base[i] = ((b * Cch) * Himg + ph * Ppat) * Wimg + pw * Ppat;
  }
  const unsigned short* wt_base = Wt + (size_t)bn * (KT * TB);

  float4 av[2];
  auto LOADA = [&](int kt) {
    int kg = kt * BK + c4 * 4;
    int c = kg >> 8, pi = (kg >> 4) & 15, pj = kg & 15;
    int off = (c * Himg + pi) * Wimg + pj;
#pragma unroll
    for (int i = 0; i < 2; ++i)
      av[i] = *reinterpret_cast<const float4*>(x + a_base[i] + off);
  };
  auto WRITEA = [&](int buf) {
#pragma unroll
    for (int i = 0; i < 2; ++i) {
      int row = r0 + 32 * i;
      int idx = (row * BK + c4 * 4) ^ ((row & 7) << 3);
      ushort4 pk = make_ushort4(f2bf(av[i].x), f2bf(av[i].y), f2bf(av[i].z), f2bf(av[i].w));
      *reinterpret_cast<ushort4*>(&As[buf][idx]) = pk;
    }
  };
  auto STAGEB = [&](int buf, int kt) {
    const unsigned short* src = wt_base + kt * TB + t * 8;
#pragma unroll
    for (int i = 0; i < 2; ++i) {
      __builtin_amdgcn_global_load_lds(
          (const __attribute__((address_space(1))) unsigned int*)(src + i * 4096),
          (__attribute__((address_space(3))) unsigned int*)(&Bs[buf][t * 8 + i * 4096]),
          16, 0, 0);
    }
  };

  f32x4 acc[2][2];
#pragma unroll
  for (int mi = 0; mi < 2; ++mi)
#pragma unroll
    for (int ni = 0; ni < 2; ++ni) acc[mi][ni] = {0.f, 0.f, 0.f, 0.f};

  LOADA(0);
  STAGEB(0, 0);
  WRITEA(0);
  __syncthreads();

  for (int kt = 0; kt < KT; ++kt) {
    const int cur = kt & 1, nxt = cur ^ 1;
    if (kt + 1 < KT) {
      LOADA(kt + 1);
      STAGEB(nxt, kt + 1);
    }
#pragma unroll
    for (int ks = 0; ks < 2; ++ks) {
      bf16x8 af[2], bfr[2];
#pragma unroll
      for (int mi = 0; mi < 2; ++mi) {
        int row = wr * 32 + mi * 16 + fr;
        int idx = (row * BK + ks * 32 + fq * 8) ^ ((row & 7) << 3);
        af[mi] = *reinterpret_cast<const bf16x8*>(&As[cur][idx]);
      }
#pragma unroll
      for (int ni = 0; ni < 2; ++ni) {
        int n = wc * 32 + ni * 16 + fr;
        int idx = (n * BK + ks * 32 + fq * 8) ^ ((n & 7) << 3);
        bfr[ni] = *reinterpret_cast<const bf16x8*>(&Bs[cur][idx]);
      }
#pragma unroll
      for (int mi = 0; mi < 2; ++mi)
#pragma unroll
        for (int ni = 0; ni < 2; ++ni)
          acc[mi][ni] = __builtin_amdgcn_mfma_f32_16x16x32_bf16(
              af[mi], bfr[ni], acc[mi][ni], 0, 0, 0);
    }
    if (kt + 1 < KT) WRITEA(nxt);
    __syncthreads();
  }

  const int n0 = bn * BN + wc * 32;
  float bv[2];
#pragma unroll
  for (int ni = 0; ni < 2; ++ni) bv[ni] = bias[n0 + ni * 16 + fr];
#pragma unroll
  for (int mi = 0; mi < 2; ++mi) {
#pragma unroll
    for (int j = 0; j < 4; ++j) {
      int m = bm * BM + wr * 32 + mi * 16 + fq * 4 + j;
      int b = m / NPATCH;
      int s = m - b * NPATCH + 1;
      float* orow = out + ((size_t)b * SEQn + s) * Dm + n0;
      const float* prow = pos + (size_t)s * Dm + n0;
#pragma unroll
      for (int ni = 0; ni < 2; ++ni) {
        int d = ni * 16 + fr;
        orow[d] = acc[mi][ni][j] + bv[ni] + prow[d];
      }
    }
  }
}

}  // namespace

extern "C" void kernel_launch(void* const* d_in, const int* in_sizes, int n_in,
                              void* d_out, int out_size, void* d_ws, size_t ws_size,
                              hipStream_t stream) {
  const float* x = (const float*)d_in[0];
  const float* W = (const float*)d_in[1];
  const float* bias = (const float*)d_in[2];
  const float* pos = (const float*)d_in[3];
  const float* cls = (const float*)d_in[4];
  float* out = (float*)d_out;

  const bool pure = ws_size >= WS_NEED;
  unsigned short* Ap = (unsigned short*)d_ws;
  unsigned short* Wt = pure ? Ap + AP_ELEMS : Ap;  // fallback: Wt at ws base
  const int nPatchBlk = pure ? PATCH_BLK : 0;

  prep_kernel<<<nPatchBlk + WPREP_BLK + CLS_BLK, 256, 0, stream>>>(
      x, W, pos, cls, Ap, Wt, out, nPatchBlk);
  if (pure)
    gemm_kernel<<<NBLK, 64, 0, stream>>>(Ap, Wt, bias, pos, out);
  else
    gemm_fb<<<NBLK, 512, 0, stream>>>(x, Wt, bias, pos, out);
}

// Round 17
// 38.811 us; speedup vs baseline: 3.0385x; 1.0546x over previous
//
#include <hip/hip_runtime.h>
#include <hip/hip_bf16.h>

namespace {

constexpr int Bsz = 64, Cch = 3, Himg = 224, Wimg = 224, Ppat = 16;
constexpr int Dm = 768, NPW = 14, NPATCH = 196, SEQn = 197;
constexpr int Mtot = Bsz * NPATCH;   // 12544
constexpr int Ktot = 768, Ntot = 768;
constexpr int BM = 64, BN = 128, BK = 64;
constexpr int MT = Mtot / BM;        // 196
constexpr int NT = Ntot / BN;        // 6
constexpr int KT = Ktot / BK;        // 12
constexpr int NBLK = MT * NT;        // 1176 (divisible by 8)
constexpr int TA = BM * BK;          // 4096 elems = 8 KB
constexpr int TB = BN * BK;          // 8192 elems = 16 KB
constexpr size_t WT_ELEMS = (size_t)NT * KT * TB;          // 589,824
constexpr int WPREP_BLK = (Ktot / 8) * Ntot / 256;         // 288
constexpr int CLS_BLK = Bsz * Dm / 256;                    // 192

typedef __attribute__((ext_vector_type(8))) short bf16x8;
typedef __attribute__((ext_vector_type(4))) float f32x4;

__device__ inline unsigned short f2bf(float f) {
  __bf16 h = (__bf16)f;  // RNE; clang fuses pairs into v_cvt_pk_bf16_f32
  union { __bf16 h; unsigned short u; } c;
  c.h = h;
  return c.u;
}

union Pack8 { unsigned short s[8]; uint4 v; };

// ---------------- prepass: W -> Wt (swizzled bf16 tiles), cls row -----------
// Wt tile (nb,kt) [128x64]: elem (n',k') at (nb*KT+kt)*TB + ((n'*BK+k')^((n'&7)<<3))
// Pre-swizzled so LINEAR global_load_lds staging yields the swizzled LDS
// image the ds_read_b128 fragment reads expect (m173 pattern).
__global__ void prep_kernel(const float* __restrict__ W,
                            const float* __restrict__ pos, const float* __restrict__ cls,
                            unsigned short* __restrict__ Wt, float* __restrict__ out) {
  const int bid = blockIdx.x;
  const int t = threadIdx.x;
  if (bid < WPREP_BLK) {  // ---- W prep (swizzled tiles)
    int cid = bid * 256 + t;
    int kc = cid / Ntot;                      // k-chunk of 8 (0..95)
    int n = cid - kc * Ntot;
    int nb = n >> 7;                          // 0..5
    int np = n & 127;
    int kt = kc >> 3;
    int k8 = (kc & 7) * 8;
    Pack8 p;
#pragma unroll
    for (int j = 0; j < 8; ++j) p.s[j] = f2bf(W[(size_t)(kc * 8 + j) * Ntot + n]);
    int sidx = (np * BK + k8) ^ ((np & 7) << 3);
    *reinterpret_cast<uint4*>(Wt + (size_t)(nb * KT + kt) * TB + sidx) = p.v;
  } else {  // ---- class-token row (s = 0)
    int i = (bid - WPREP_BLK) * 256 + t;
    int b = i / Dm;
    int d = i - b * Dm;
    out[(size_t)b * (SEQn * Dm) + d] = cls[d] + pos[d];
  }
}

// ---------------- FUSED GEMM: in-kernel A staging, single buffer ------------
// R10's proven skeleton (4 waves 2x2 of 32x64, 24 KB LDS, grid 1176 all
// co-resident) with the A-prepass folded in: per step, gather the 64x64 A
// sub-tile from x as fp32 (4 float4/thread, 64B row segments, L2-hot via the
// bn-fastest XCD chunk ordering), cvt to bf16 and ds_write at the swizzled
// offset (2 lanes/bank = free). Eliminates the Ap round-trip (~39 MB) and a
// launch. No registers live across the MFMA phase (R15 scratch lesson).
__global__ __launch_bounds__(256, 5)
void gemm_kernel(const float* __restrict__ x, const unsigned short* __restrict__ Wt,
                 const float* __restrict__ bias, const float* __restrict__ pos,
                 float* __restrict__ out) {
  __shared__ unsigned short A[TA];     // 8 KB
  __shared__ unsigned short B[TB];     // 16 KB

  // XCD-chunked bijective swizzle (NBLK % 8 == 0); bn fastest within a chunk
  // -> this bm's x panel (192 KB fp32) re-read 6x back-to-back in one L2.
  const int orig = blockIdx.x;
  const int wg = (orig & 7) * (NBLK / 8) + (orig >> 3);
  const int bm = wg / NT;
  const int bn = wg - bm * NT;

  const int t = threadIdx.x;
  const int lane = t & 63;
  const int wid = t >> 6;              // 4 waves: 2 (M) x 2 (N), each 32x64
  const int wr = wid >> 1, wc = wid & 1;
  const int fr = lane & 15, fq = lane >> 4;

  // A staging geometry: thread covers float4 k-group c4, rows r0 + 16*i
  const int c4 = t & 15;
  const int r0 = t >> 4;
  int a_base[4];
#pragma unroll
  for (int i = 0; i < 4; ++i) {
    int m = bm * BM + r0 + 16 * i;
    int b = m / NPATCH;
    int pidx = m - b * NPATCH;
    int ph = pidx / NPW;
    int pw = pidx - ph * NPW;
    a_base[i] = ((b * Cch) * Himg + ph * Ppat) * Wimg + pw * Ppat;
  }
  const unsigned short* bSrc = Wt + (size_t)(bn * KT) * TB + t * 8;

  f32x4 acc[2][4];
#pragma unroll
  for (int mi = 0; mi < 2; ++mi)
#pragma unroll
    for (int ni = 0; ni < 4; ++ni) acc[mi][ni] = {0.f, 0.f, 0.f, 0.f};

  for (int kt = 0; kt < KT; ++kt) {
    // ---- stage phase: x loads + B DMA in flight together, then cvt+write
    float4 av[4];
    {
      int kg = kt * BK + c4 * 4;
      int c = kg >> 8, pi = (kg >> 4) & 15, pj = kg & 15;
      int off = (c * Himg + pi) * Wimg + pj;
#pragma unroll
      for (int i = 0; i < 4; ++i)
        av[i] = *reinterpret_cast<const float4*>(x + a_base[i] + off);
    }
#pragma unroll
    for (int i = 0; i < 4; ++i)
      __builtin_amdgcn_global_load_lds(
          (const __attribute__((address_space(1))) unsigned int*)(bSrc + kt * TB + i * 2048),
          (__attribute__((address_space(3))) unsigned int*)(&B[t * 8 + i * 2048]),
          16, 0, 0);
#pragma unroll
    for (int i = 0; i < 4; ++i) {
      int row = r0 + 16 * i;
      int idx = (row * BK + c4 * 4) ^ ((row & 7) << 3);
      ushort4 pk = make_ushort4(f2bf(av[i].x), f2bf(av[i].y), f2bf(av[i].z), f2bf(av[i].w));
      *reinterpret_cast<ushort4*>(&A[idx]) = pk;
    }
    __syncthreads();                   // drains DMA (vmcnt) + ds_writes (lgkm)
    // ---- compute phase
#pragma unroll
    for (int ks = 0; ks < 2; ++ks) {
      bf16x8 af[2], bfr[4];
#pragma unroll
      for (int mi = 0; mi < 2; ++mi) {
        int row = wr * 32 + mi * 16 + fr;
        int idx = (row * BK + ks * 32 + fq * 8) ^ ((row & 7) << 3);
        af[mi] = *reinterpret_cast<const bf16x8*>(&A[idx]);
      }
#pragma unroll
      for (int ni = 0; ni < 4; ++ni) {
        int n = wc * 64 + ni * 16 + fr;
        int idx = (n * BK + ks * 32 + fq * 8) ^ ((n & 7) << 3);
        bfr[ni] = *reinterpret_cast<const bf16x8*>(&B[idx]);
      }
#pragma unroll
      for (int mi = 0; mi < 2; ++mi)
#pragma unroll
        for (int ni = 0; ni < 4; ++ni)
          acc[mi][ni] = __builtin_amdgcn_mfma_f32_16x16x32_bf16(
              af[mi], bfr[ni], acc[mi][ni], 0, 0, 0);
    }
    if (kt + 1 < KT) __syncthreads();  // all reads done before next overwrite
  }

  // ---- epilogue: R5/R10 pattern (measured WRITE_SIZE == ideal 37.6 MB):
  // per (mi,j) the 4 ni-stores are adjacent, covering 256B contiguous per row.
  const int n0 = bn * BN + wc * 64;
  float bv[4];
#pragma unroll
  for (int ni = 0; ni < 4; ++ni) bv[ni] = bias[n0 + ni * 16 + fr];
#pragma unroll
  for (int mi = 0; mi < 2; ++mi) {
#pragma unroll
    for (int j = 0; j < 4; ++j) {
      int m = bm * BM + wr * 32 + mi * 16 + fq * 4 + j;
      int b = m / NPATCH;
      int s = m - b * NPATCH + 1;  // +1: class token at s=0
      float* orow = out + ((size_t)b * SEQn + s) * Dm + n0;
      const float* prow = pos + (size_t)s * Dm + n0;
#pragma unroll
      for (int ni = 0; ni < 4; ++ni) {
        int d = ni * 16 + fr;
        orow[d] = acc[mi][ni][j] + bv[ni] + prow[d];
      }
    }
  }
}

}  // namespace

extern "C" void kernel_launch(void* const* d_in, const int* in_sizes, int n_in,
                              void* d_out, int out_size, void* d_ws, size_t ws_size,
                              hipStream_t stream) {
  const float* x = (const float*)d_in[0];
  const float* W = (const float*)d_in[1];
  const float* bias = (const float*)d_in[2];
  const float* pos = (const float*)d_in[3];
  const float* cls = (const float*)d_in[4];
  float* out = (float*)d_out;
  unsigned short* Wt = (unsigned short*)d_ws;  // needs 1.18 MB

  prep_kernel<<<WPREP_BLK + CLS_BLK, 256, 0, stream>>>(W, pos, cls, Wt, out);
  gemm_kernel<<<NBLK, 256, 0, stream>>>(x, Wt, bias, pos, out);
}